// Round 2
// baseline (199.516 us; speedup 1.0000x reference)
//
#include <hip/hip_runtime.h>

#define NT 16   // nodes per block

typedef __attribute__((ext_vector_type(4))) float f32x4;
typedef __attribute__((ext_vector_type(8))) __bf16 bf16x8;
typedef __attribute__((ext_vector_type(8))) unsigned short u16x8;
typedef __attribute__((ext_vector_type(2))) unsigned int u32x2;

__device__ __forceinline__ unsigned short f2bf(float f) {
    unsigned u = __builtin_bit_cast(unsigned, f);
    u += 0x7fffu + ((u >> 16) & 1u);   // RNE
    return (unsigned short)(u >> 16);
}
__device__ __forceinline__ unsigned pack2(float a, float b) {
    return (unsigned)f2bf(a) | ((unsigned)f2bf(b) << 16);
}

// Pre-arrange B matrices in MFMA-fragment-major order (bf16), weights pre-scaled.
// frag element index: ((sel*8 + kt)*8 + nt)*512 + lane*8 + j
// value = Bsel[k = kt*32 + (lane>>4)*8 + j][w = nt*16 + (lane&15)]
// B0 = [ALPHA*W1 ; ALPHA*INV_SQRT3*W4],  B1 = [ALPHA*W2 ; ALPHA*W3]
__global__ void build_bfrag_kernel(const float* __restrict__ W1,
                                   const float* __restrict__ W2,
                                   const float* __restrict__ W3,
                                   const float* __restrict__ W4,
                                   unsigned short* __restrict__ bfrag) {
    const float ALPHA = 0.0625f;                 // 1/sqrt(2*128)
    const float INV_SQRT3 = 0.57735026918962576f;
    int i = blockIdx.x * 256 + threadIdx.x;      // 0..65535
    int j   = i & 7;
    int l   = (i >> 3) & 63;
    int nt  = (i >> 9) & 7;
    int kt  = (i >> 12) & 7;
    int sel = (i >> 15) & 1;
    int k = kt * 32 + (l >> 4) * 8 + j;
    int w = nt * 16 + (l & 15);
    float v;
    if (sel == 0) {
        v = (k < 128) ? ALPHA * W1[k * 128 + w]
                      : ALPHA * INV_SQRT3 * W4[(k - 128) * 128 + w];
    } else {
        v = (k < 128) ? ALPHA * W2[k * 128 + w]
                      : ALPHA * W3[(k - 128) * 128 + w];
    }
    bfrag[i] = f2bf(v);
}

__global__ __launch_bounds__(256, 4)
void o3tp_kernel(const float* __restrict__ x, const float* __restrict__ y,
                 const float* __restrict__ bias,
                 const unsigned short* __restrict__ bfrag,
                 float* __restrict__ out) {
    // smem: phase 1 = Aeff[4 types][16 rows][256 k] bf16 (XOR-swizzled rows), 8 KB/type
    //       phase 3 = C  [4 types][16 rows][128 w] f32   (same 32 KB, slab aliases; XOR-swizzled cols)
    __shared__ __align__(16) unsigned char smem[32768];
    const int tid = threadIdx.x;
    const int nb  = blockIdx.x * NT;

    // ---------------- producer: build Aeff in LDS ----------------
    {
        const int g  = tid & 31;   // u-group of 4
        const int n0 = tid >> 5;   // 0..7
        #pragma unroll
        for (int pass = 0; pass < 2; ++pass) {
            const int n = n0 + pass * 8;                 // local node 0..15
            const long row = (long)(nb + n) * 512;
            f32x4 X0 = *(const f32x4*)(x + row + 4 * g);
            f32x4 T0 = *(const f32x4*)(x + row + 128 + 12 * g);
            f32x4 T1 = *(const f32x4*)(x + row + 128 + 12 * g + 4);
            f32x4 T2 = *(const f32x4*)(x + row + 128 + 12 * g + 8);
            f32x4 Y  = *(const f32x4*)(y + (long)(nb + n) * 4);
            float y0 = Y[0], ya = Y[1], yb = Y[2], yc = Y[3];
            float e0 = T0[0], e1 = T0[1], e2  = T0[2], e3  = T0[3];
            float e4 = T1[0], e5 = T1[1], e6  = T1[2], e7  = T1[3];
            float e8 = T2[0], e9 = T2[1], e10 = T2[2], e11 = T2[3];
            // s[u] = x1[u,:] . y1
            float s0 = e0 * ya + e1  * yb + e2  * yc;
            float s1 = e3 * ya + e4  * yb + e5  * yc;
            float s2 = e6 * ya + e7  * yb + e8  * yc;
            float s3 = e9 * ya + e10 * yb + e11 * yc;
            const int swz  = (n & 7) << 4;
            const int base = n * 512;
            const int klo  = ((8 * g)       ^ swz) + base;
            const int khi  = ((256 + 8 * g) ^ swz) + base;
            auto WR = [&](int t, int kb, float a, float b2, float c, float d) {
                u32x2 v; v[0] = pack2(a, b2); v[1] = pack2(c, d);
                *(u32x2*)(smem + t * 8192 + kb) = v;
            };
            WR(0, klo, y0 * X0[0], y0 * X0[1], y0 * X0[2], y0 * X0[3]);
            WR(0, khi, s0, s1, s2, s3);
            WR(1, klo, ya * X0[0], ya * X0[1], ya * X0[2], ya * X0[3]);
            WR(1, khi, y0 * e0, y0 * e3, y0 * e6, y0 * e9);
            WR(2, klo, yb * X0[0], yb * X0[1], yb * X0[2], yb * X0[3]);
            WR(2, khi, y0 * e1, y0 * e4, y0 * e7, y0 * e10);
            WR(3, klo, yc * X0[0], yc * X0[1], yc * X0[2], yc * X0[3]);
            WR(3, khi, y0 * e2, y0 * e5, y0 * e8, y0 * e11);
        }
    }
    __syncthreads();

    // ---------------- MFMA: wave t computes C_t (16x128) ----------------
    const int wv   = tid >> 6;     // wave id == output type
    const int l    = tid & 63;
    const int lrow = l & 15;
    const int lk   = l >> 4;

    u16x8 afr[8];
    #pragma unroll
    for (int kt = 0; kt < 8; ++kt) {
        int r = lrow;
        int kbyte = kt * 64 + lk * 16;
        int addr = wv * 8192 + r * 512 + (kbyte ^ ((r & 7) << 4));
        afr[kt] = *(const u16x8*)(smem + addr);
    }

    f32x4 acc[8];
    #pragma unroll
    for (int nt = 0; nt < 8; ++nt) {
        f32x4 z = {0.f, 0.f, 0.f, 0.f};
        acc[nt] = z;
    }

    const unsigned short* bbase = bfrag + (wv ? 32768 : 0) + l * 8;
    #pragma unroll
    for (int nt = 0; nt < 8; ++nt) {
        u16x8 bfr[8];
        #pragma unroll
        for (int kt = 0; kt < 8; ++kt)
            bfr[kt] = *(const u16x8*)(bbase + (kt * 8 + nt) * 512);
        #pragma unroll
        for (int kt = 0; kt < 8; ++kt) {
            acc[nt] = __builtin_amdgcn_mfma_f32_16x16x32_bf16(
                __builtin_bit_cast(bf16x8, afr[kt]),
                __builtin_bit_cast(bf16x8, bfr[kt]), acc[nt], 0, 0, 0);
        }
    }

    // bias only on type 0 (added after the ALPHA-scaled sums, as in the reference)
    if (wv == 0) {
        #pragma unroll
        for (int nt = 0; nt < 8; ++nt) {
            float bv = bias[nt * 16 + lrow];
            #pragma unroll
            for (int j = 0; j < 4; ++j)
                acc[nt][j] += bv;
        }
    }

    // store C_t into own slab (in-wave DS ordering makes this safe, no barrier needed)
    // C/D layout: row(node) = (lane>>4)*4 + reg, col(w) = lane&15   [m89-verified]
    // col XOR-swizzled by row so the column-strided scalar stores are 2-way (free)
    float* cslab = (float*)(smem + wv * 8192);
    #pragma unroll
    for (int nt = 0; nt < 8; ++nt)
        #pragma unroll
        for (int j = 0; j < 4; ++j) {
            int r = lk * 4 + j;
            int c = nt * 16 + lrow;
            cslab[r * 128 + (c ^ ((r & 7) << 2))] = acc[nt][j];
        }

    __syncthreads();

    // ---------------- coalesced writeout with w*3+i interleave ----------------
    const float* call = (const float*)smem;   // [type][16][128] f32, col-swizzled
    #pragma unroll 4
    for (int it = 0; it < 8; ++it) {
        int idx = it * 256 + tid;    // 0..2047
        int n = idx >> 7;            // local node
        int p = idx & 127;           // float4 position within the 512-float row
        int swz = (n & 7) << 2;
        f32x4 v;
        if (p < 32) {
            // swz has bits 2..4 only (float-index), so 4-float groups stay contiguous
            v = *(const f32x4*)(call + n * 128 + ((p * 4) ^ swz));   // out0 block
        } else {
            int q = p * 4 - 128;     // flat index into out1 region (= w*3 + i)
            #pragma unroll
            for (int c = 0; c < 4; ++c) {
                int qq = q + c;
                int w  = qq / 3;
                int i3 = qq - w * 3;
                v[c] = call[(1 + i3) * 2048 + n * 128 + (w ^ swz)];
            }
        }
        *(f32x4*)(out + (long)(nb + n) * 512 + p * 4) = v;
    }
}

extern "C" void kernel_launch(void* const* d_in, const int* in_sizes, int n_in,
                              void* d_out, int out_size, void* d_ws, size_t ws_size,
                              hipStream_t stream) {
    const float* x  = (const float*)d_in[0];
    const float* y  = (const float*)d_in[1];
    const float* W1 = (const float*)d_in[2];
    const float* W2 = (const float*)d_in[3];
    const float* W3 = (const float*)d_in[4];
    const float* W4 = (const float*)d_in[5];
    const float* b  = (const float*)d_in[6];
    float* out = (float*)d_out;
    unsigned short* bfrag = (unsigned short*)d_ws;   // 65536 bf16 = 128 KB

    int n_nodes = in_sizes[0] / 512;
    hipLaunchKernelGGL(build_bfrag_kernel, dim3(256), dim3(256), 0, stream,
                       W1, W2, W3, W4, bfrag);
    hipLaunchKernelGGL(o3tp_kernel, dim3(n_nodes / NT), dim3(256), 0, stream,
                       x, y, b, bfrag, out);
}

// Round 3
// 118.674 us; speedup vs baseline: 1.6812x; 1.6812x over previous
//
#include <hip/hip_runtime.h>

#define TILE_NODES 32
#define NBLOCKS 512

typedef __attribute__((ext_vector_type(4))) float f32x4;
typedef __attribute__((ext_vector_type(8))) __bf16 bf16x8;
typedef __attribute__((ext_vector_type(8))) unsigned short u16x8;

__device__ __forceinline__ unsigned short f2bf(float f) {
    unsigned u = __builtin_bit_cast(unsigned, f);
    u += 0x7fffu + ((u >> 16) & 1u);   // RNE
    return (unsigned short)(u >> 16);
}

// B fragments, fragment-major, weights pre-scaled.
// elem i = ((T*4 + kt)*8 + ct)*512 + lane*8 + j
// value  = scale_T * W_T[k = kt*32 + (lane>>4)*8 + j][col = ct*16 + (lane&15)]
// T: 0=alpha*W1, 1=alpha*W2, 2=alpha*W3, 3=(alpha/sqrt3)*W4
__global__ void build_bfrag_kernel(const float* __restrict__ W1,
                                   const float* __restrict__ W2,
                                   const float* __restrict__ W3,
                                   const float* __restrict__ W4,
                                   unsigned short* __restrict__ bfrag) {
    const float ALPHA = 0.0625f;                       // 1/sqrt(2*128)
    const float A3    = 0.0625f * 0.57735026918962576f;
    int i = blockIdx.x * 256 + threadIdx.x;            // 0..65535
    int j  = i & 7;
    int l  = (i >> 3) & 63;
    int ct = (i >> 9) & 7;
    int kt = (i >> 12) & 3;
    int T  = (i >> 14) & 3;
    int k   = kt * 32 + ((l >> 4) & 3) * 8 + j;
    int col = ct * 16 + (l & 15);
    const float* W = (T == 0) ? W1 : (T == 1) ? W2 : (T == 2) ? W3 : W4;
    float s = (T == 3) ? A3 : ALPHA;
    bfrag[i] = f2bf(s * W[k * 128 + col]);
}

__global__ __launch_bounds__(512, 2)
void o3tp_kernel(const float* __restrict__ x, const float* __restrict__ y,
                 const float* __restrict__ bias,
                 const unsigned short* __restrict__ bfrag,
                 float* __restrict__ out, int tiles_per_block) {
    // 2 buffers x (4 chunks x 32 nodes x 128 bf16) = 64 KB.
    // chunk slab: c*8192; row: node*256; byte-in-row: (k*2) ^ ((node&7)<<4)  [16B-granular XOR swizzle]
    __shared__ __align__(16) unsigned char smem[65536];
    const int tid = threadIdx.x;
    const int w   = tid >> 6;     // wave id == column tile ct
    const int l   = tid & 63;
    const int lk  = l >> 4;
    const int lr  = l & 15;

    // ---- B fragments: resident in registers for the whole kernel ----
    u16x8 bq[4][4];
    #pragma unroll
    for (int T = 0; T < 4; ++T)
        #pragma unroll
        for (int kt = 0; kt < 4; ++kt)
            bq[T][kt] = *(const u16x8*)(bfrag + (((T * 4 + kt) * 8 + w) << 9) + l * 8);
    const float bias_v = bias[w * 16 + lr];

    // staging assignment: one (node, k-octet) per thread
    const int n_  = tid >> 4;     // 0..31
    const int G   = tid & 15;     // 0..15
    const int swz = (n_ & 7) << 4;

    const long tile0 = (long)blockIdx.x * tiles_per_block;

    f32x4 X0a, X0b, Ta, Tb, Tc, Td, Te, Tf;
    auto LOADS = [&](long tile) {
        const float* bp = x + (tile * TILE_NODES + n_) * 512;
        X0a = *(const f32x4*)(bp + 8 * G);
        X0b = *(const f32x4*)(bp + 8 * G + 4);
        const float* tp = bp + 128 + 24 * G;
        Ta = *(const f32x4*)(tp);      Tb = *(const f32x4*)(tp + 4);
        Tc = *(const f32x4*)(tp + 8);  Td = *(const f32x4*)(tp + 12);
        Te = *(const f32x4*)(tp + 16); Tf = *(const f32x4*)(tp + 20);
    };
    auto WRITE = [&](int buf) {
        unsigned char* base = smem + buf * 32768 + n_ * 256 + ((16 * G) ^ swz);
        u16x8 v;
        v[0] = f2bf(X0a[0]); v[1] = f2bf(X0a[1]); v[2] = f2bf(X0a[2]); v[3] = f2bf(X0a[3]);
        v[4] = f2bf(X0b[0]); v[5] = f2bf(X0b[1]); v[6] = f2bf(X0b[2]); v[7] = f2bf(X0b[3]);
        *(u16x8*)(base) = v;                                   // chunk 0 (x0)
        float t[24] = {Ta[0],Ta[1],Ta[2],Ta[3], Tb[0],Tb[1],Tb[2],Tb[3],
                       Tc[0],Tc[1],Tc[2],Tc[3], Td[0],Td[1],Td[2],Td[3],
                       Te[0],Te[1],Te[2],Te[3], Tf[0],Tf[1],Tf[2],Tf[3]};
        #pragma unroll
        for (int i3 = 0; i3 < 3; ++i3) {                       // chunks 1..3 (x1_i)
            u16x8 u;
            #pragma unroll
            for (int up = 0; up < 8; ++up) u[up] = f2bf(t[3 * up + i3]);
            *(u16x8*)(base + (i3 + 1) * 8192) = u;
        }
    };

    // prologue
    LOADS(tile0);
    WRITE(0);

    for (int it = 0; it < tiles_per_block; ++it) {
        const long tile = tile0 + it;
        __syncthreads();                         // buf[it&1] ready for all waves
        if (it + 1 < tiles_per_block) LOADS(tile + 1);   // in flight under compute

        // ---- MFMA: 8 unscaled products for this wave's 16-col slice ----
        const unsigned char* ab = smem + (it & 1) * 32768;
        f32x4 M1[2] = {}, M2[2] = {}, M3[3][2] = {}, M4[3][2] = {};
        #pragma unroll
        for (int c = 0; c < 4; ++c) {
            u16x8 ar[2][4];
            #pragma unroll
            for (int m = 0; m < 2; ++m)
                #pragma unroll
                for (int kt = 0; kt < 4; ++kt)
                    ar[m][kt] = *(const u16x8*)(ab + c * 8192 + (m * 16 + lr) * 256
                                                + ((kt * 64 + lk * 16) ^ ((l & 7) << 4)));
            #pragma unroll
            for (int m = 0; m < 2; ++m)
                #pragma unroll
                for (int kt = 0; kt < 4; ++kt) {
                    if (c == 0) {
                        M1[m] = __builtin_amdgcn_mfma_f32_16x16x32_bf16(
                            __builtin_bit_cast(bf16x8, ar[m][kt]),
                            __builtin_bit_cast(bf16x8, bq[0][kt]), M1[m], 0, 0, 0);
                        M2[m] = __builtin_amdgcn_mfma_f32_16x16x32_bf16(
                            __builtin_bit_cast(bf16x8, ar[m][kt]),
                            __builtin_bit_cast(bf16x8, bq[1][kt]), M2[m], 0, 0, 0);
                    } else {
                        M3[c - 1][m] = __builtin_amdgcn_mfma_f32_16x16x32_bf16(
                            __builtin_bit_cast(bf16x8, ar[m][kt]),
                            __builtin_bit_cast(bf16x8, bq[2][kt]), M3[c - 1][m], 0, 0, 0);
                        M4[c - 1][m] = __builtin_amdgcn_mfma_f32_16x16x32_bf16(
                            __builtin_bit_cast(bf16x8, ar[m][kt]),
                            __builtin_bit_cast(bf16x8, bq[3][kt]), M4[c - 1][m], 0, 0, 0);
                    }
                }
        }

        // ---- per-node y-combination in C-registers, direct global store ----
        // C/D: row(node) = lk*4 + reg (+16m), col = lr   [verified R1]
        const long nb = tile * TILE_NODES;
        #pragma unroll
        for (int m = 0; m < 2; ++m)
            #pragma unroll
            for (int j = 0; j < 4; ++j) {
                const int nl = m * 16 + lk * 4 + j;
                const f32x4 yv = *(const f32x4*)(y + (nb + nl) * 4);   // 16-lane broadcast, L1-hot
                float* rp = out + (nb + nl) * 512;
                const int c0 = w * 16 + lr;
                rp[c0] = yv[0] * M1[m][j] + yv[1] * M4[0][m][j]
                       + yv[2] * M4[1][m][j] + yv[3] * M4[2][m][j] + bias_v;
                rp[128 + 3 * c0 + 0] = yv[1] * M2[m][j] + yv[0] * M3[0][m][j];
                rp[128 + 3 * c0 + 1] = yv[2] * M2[m][j] + yv[0] * M3[1][m][j];
                rp[128 + 3 * c0 + 2] = yv[3] * M2[m][j] + yv[0] * M3[2][m][j];
            }

        if (it + 1 < tiles_per_block) WRITE((it + 1) & 1);   // consume staged regs
    }
}

extern "C" void kernel_launch(void* const* d_in, const int* in_sizes, int n_in,
                              void* d_out, int out_size, void* d_ws, size_t ws_size,
                              hipStream_t stream) {
    const float* x  = (const float*)d_in[0];
    const float* y  = (const float*)d_in[1];
    const float* W1 = (const float*)d_in[2];
    const float* W2 = (const float*)d_in[3];
    const float* W3 = (const float*)d_in[4];
    const float* W4 = (const float*)d_in[5];
    const float* b  = (const float*)d_in[6];
    float* out = (float*)d_out;
    unsigned short* bfrag = (unsigned short*)d_ws;   // 65536 bf16 = 128 KB

    int n_nodes = in_sizes[0] / 512;
    int ntiles  = n_nodes / TILE_NODES;
    int tpb     = ntiles / NBLOCKS;                  // 8 for N=131072

    hipLaunchKernelGGL(build_bfrag_kernel, dim3(256), dim3(256), 0, stream,
                       W1, W2, W3, W4, bfrag);
    hipLaunchKernelGGL(o3tp_kernel, dim3(NBLOCKS), dim3(512), 0, stream,
                       x, y, b, bfrag, out, tpb);
}